// Round 1
// baseline (326.632 us; speedup 1.0000x reference)
//
#include <hip/hip_runtime.h>

__device__ __forceinline__ float clamp01(float x) {
    return fminf(fmaxf(x, 0.0f), 1.0f);
}

// Per-pixel RGB -> HSV -> adjust -> RGB, mirroring the JAX reference exactly.
__device__ __forceinline__ void hsv_px(float r, float g, float b,
                                       float dh, float ds,
                                       float& ro, float& go, float& bo) {
    float maxc = fmaxf(r, fmaxf(g, b));
    float minc = fminf(r, fminf(g, b));
    float cr   = maxc - minc;
    bool  eq   = (cr == 0.0f);                 // maxc == minc
    float s    = eq ? 0.0f : cr / maxc;        // cr / where(eqc, 1, maxc); cr==0 when eq
    float inv  = eq ? 1.0f : 1.0f / cr;        // 1 / cr_div
    float rc = (maxc - r) * inv;
    float gc = (maxc - g) * inv;
    float bc = (maxc - b) * inv;
    // hr/hg/hb masks are mutually exclusive with this priority order:
    float hraw;
    if (maxc == r)      hraw = bc - gc;                 // (maxc==r)
    else if (maxc == g) hraw = 2.0f + rc - bc;          // (maxc==g) & (maxc!=r)
    else                hraw = 4.0f + gc - rc;          // (maxc!=g) & (maxc!=r)
    float h = fmodf(hraw, 6.0f);
    if (h < 0.0f) h += 6.0f;                   // jnp.mod semantics (floor-mod)
    h *= (1.0f / 6.0f);

    // transform
    h += dh;
    h -= floorf(h);                            // mod(h + dh, 1.0)
    s  = clamp01(s * ds);                      // clip(sat * ds, 0, 1)

    // hsv -> rgb
    float v  = maxc;
    float h6 = h * 6.0f;
    float fi = floorf(h6);
    float f  = h6 - fi;
    int   i  = ((int)fi) % 6;                  // h6 in [0,6]; ==6 folds to i=0,f=0 (continuous)
    float p = clamp01(v * (1.0f - s));
    float q = clamp01(v * (1.0f - s * f));
    float t = clamp01(v * (1.0f - s * (1.0f - f)));
    // r = sel(v,q,p,p,t,v); g = sel(t,v,v,q,p,p); b = sel(p,p,t,v,v,q)
    ro = (i == 0 || i == 5) ? v : (i == 1) ? q : (i == 4) ? t : p;
    go = (i == 1 || i == 2) ? v : (i == 0) ? t : (i == 3) ? q : p;
    bo = (i == 3 || i == 4) ? v : (i == 2) ? t : (i == 5) ? q : p;
}

__global__ __launch_bounds__(256)
void AdjustHueSaturation_60455959658579_kernel(const float* __restrict__ img,
                                               const float* __restrict__ params,
                                               float* __restrict__ out,
                                               int HW, int quadsPerImg, int total) {
    int gid = blockIdx.x * blockDim.x + threadIdx.x;
    if (gid >= total) return;
    int b   = gid / quadsPerImg;               // image index
    int off = (gid - b * quadsPerImg) * 4;     // pixel offset within image

    float dh = params[2 * b];
    float ds = params[2 * b + 1];

    size_t base = (size_t)b * 3u * (size_t)HW + (size_t)off;
    const float4 r4 = *reinterpret_cast<const float4*>(img + base);
    const float4 g4 = *reinterpret_cast<const float4*>(img + base + (size_t)HW);
    const float4 b4 = *reinterpret_cast<const float4*>(img + base + 2 * (size_t)HW);

    float4 ro4, go4, bo4;
    hsv_px(r4.x, g4.x, b4.x, dh, ds, ro4.x, go4.x, bo4.x);
    hsv_px(r4.y, g4.y, b4.y, dh, ds, ro4.y, go4.y, bo4.y);
    hsv_px(r4.z, g4.z, b4.z, dh, ds, ro4.z, go4.z, bo4.z);
    hsv_px(r4.w, g4.w, b4.w, dh, ds, ro4.w, go4.w, bo4.w);

    *reinterpret_cast<float4*>(out + base)                  = ro4;
    *reinterpret_cast<float4*>(out + base + (size_t)HW)     = go4;
    *reinterpret_cast<float4*>(out + base + 2 * (size_t)HW) = bo4;
}

extern "C" void kernel_launch(void* const* d_in, const int* in_sizes, int n_in,
                              void* d_out, int out_size, void* d_ws, size_t ws_size,
                              hipStream_t stream) {
    const float* img    = (const float*)d_in[0];
    const float* params = (const float*)d_in[1];
    float*       out    = (float*)d_out;

    int total_elems = in_sizes[0];          // B*3*H*W
    int Bn          = in_sizes[1] / 2;      // 64
    int HW          = total_elems / (3 * Bn);
    int quads       = HW / 4;               // HW divisible by 4 (W=512)
    int total       = Bn * quads;

    int block = 256;
    int grid  = (total + block - 1) / block;
    AdjustHueSaturation_60455959658579_kernel<<<grid, block, 0, stream>>>(
        img, params, out, HW, quads, total);
}

// Round 4
// 314.234 us; speedup vs baseline: 1.0395x; 1.0395x over previous
//
#include <hip/hip_runtime.h>

typedef float floatx4 __attribute__((ext_vector_type(4)));

struct RGB { float r, g, b; };

__device__ __forceinline__ float clamp01(float x) {
    return fminf(fmaxf(x, 0.0f), 1.0f);
}

// Per-pixel RGB -> HSV -> (hue shift, sat scale) -> RGB.
// Algebraically simplified vs the JAX reference (tolerance 2e-2 allows
// v_rcp_f32 instead of exact divides, and the fmod chain collapses since
// hraw is provably in (-1, 5)).
__device__ __forceinline__ RGB hsv_px(float r, float g, float b,
                                      float dh, float ds) {
    float maxc = fmaxf(r, fmaxf(g, b));
    float minc = fminf(r, fminf(g, b));
    float cr   = maxc - minc;
    bool  eq   = (cr == 0.0f);
    // fast reciprocals (~1 ulp); eq-guarded so gray pixels give s=0, h0=0
    float inv  = eq ? 0.0f : __builtin_amdgcn_rcpf(cr);
    float s    = eq ? 0.0f : cr * __builtin_amdgcn_rcpf(maxc);

    // hraw in sixths: r-max -> (g-b)/cr in [-1,1]; g-max -> 2+(b-r)/cr in [1,3];
    // b-max -> 4+(r-g)/cr in [3,5].
    float h0 = (maxc == r) ? (g - b) * inv
             : (maxc == g) ? fmaf(b - r, inv, 2.0f)
                           : fmaf(r - g, inv, 4.0f);

    // mod(mod(h0,6)/6 + dh, 1) == frac(h0/6 + dh)
    float hh = fmaf(h0, (1.0f / 6.0f), dh);
    hh -= floorf(hh);                       // in [0,1)
    s = clamp01(s * ds);

    float v  = maxc;
    float h6 = hh * 6.0f;
    float fi = floorf(h6);
    float f  = h6 - fi;
    int   i  = (int)fi;
    if (i >= 6) i -= 6;                     // reference's i % 6 guard
    float p = clamp01(v * (1.0f - s));
    float q = clamp01(v * fmaf(-s, f, 1.0f));
    float t = clamp01(v * fmaf(-s, 1.0f - f, 1.0f));
    // r = sel(v,q,p,p,t,v); g = sel(t,v,v,q,p,p); b = sel(p,p,t,v,v,q)
    RGB o;
    o.r = (i == 0 || i == 5) ? v : (i == 1) ? q : (i == 4) ? t : p;
    o.g = (i == 1 || i == 2) ? v : (i == 0) ? t : (i == 3) ? q : p;
    o.b = (i == 3 || i == 4) ? v : (i == 2) ? t : (i == 5) ? q : p;
    return o;
}

__global__ __launch_bounds__(256)
void AdjustHueSaturation_60455959658579_kernel(const float* __restrict__ img,
                                               const float* __restrict__ params,
                                               float* __restrict__ out,
                                               int HW, int quadsPerImg, int total) {
    int gid = blockIdx.x * blockDim.x + threadIdx.x;
    if (gid >= total) return;
    int b   = gid / quadsPerImg;               // image index
    int off = (gid - b * quadsPerImg) * 4;     // pixel offset within image

    float dh = params[2 * b];
    float ds = params[2 * b + 1];

    size_t base = (size_t)b * 3u * (size_t)HW + (size_t)off;
    floatx4 r4 = __builtin_nontemporal_load(
        reinterpret_cast<const floatx4*>(img + base));
    floatx4 g4 = __builtin_nontemporal_load(
        reinterpret_cast<const floatx4*>(img + base + (size_t)HW));
    floatx4 b4 = __builtin_nontemporal_load(
        reinterpret_cast<const floatx4*>(img + base + 2 * (size_t)HW));

    floatx4 ro4, go4, bo4;
    {
        RGB o = hsv_px(r4.x, g4.x, b4.x, dh, ds);
        ro4.x = o.r; go4.x = o.g; bo4.x = o.b;
    }
    {
        RGB o = hsv_px(r4.y, g4.y, b4.y, dh, ds);
        ro4.y = o.r; go4.y = o.g; bo4.y = o.b;
    }
    {
        RGB o = hsv_px(r4.z, g4.z, b4.z, dh, ds);
        ro4.z = o.r; go4.z = o.g; bo4.z = o.b;
    }
    {
        RGB o = hsv_px(r4.w, g4.w, b4.w, dh, ds);
        ro4.w = o.r; go4.w = o.g; bo4.w = o.b;
    }

    __builtin_nontemporal_store(ro4, reinterpret_cast<floatx4*>(out + base));
    __builtin_nontemporal_store(go4, reinterpret_cast<floatx4*>(out + base + (size_t)HW));
    __builtin_nontemporal_store(bo4, reinterpret_cast<floatx4*>(out + base + 2 * (size_t)HW));
}

extern "C" void kernel_launch(void* const* d_in, const int* in_sizes, int n_in,
                              void* d_out, int out_size, void* d_ws, size_t ws_size,
                              hipStream_t stream) {
    const float* img    = (const float*)d_in[0];
    const float* params = (const float*)d_in[1];
    float*       out    = (float*)d_out;

    int total_elems = in_sizes[0];          // B*3*H*W
    int Bn          = in_sizes[1] / 2;      // 64
    int HW          = total_elems / (3 * Bn);
    int quads       = HW / 4;               // HW divisible by 4 (W=512)
    int total       = Bn * quads;

    int block = 256;
    int grid  = (total + block - 1) / block;
    AdjustHueSaturation_60455959658579_kernel<<<grid, block, 0, stream>>>(
        img, params, out, HW, quads, total);
}